// Round 2
// baseline (4093.424 us; speedup 1.0000x reference)
//
#include <hip/hip_runtime.h>

typedef _Float16 f16;
typedef _Float16 f16x2 __attribute__((ext_vector_type(2)));

#define EMBED 256
#define HID 512
#define KD 768     // EMBED + HID
#define KD2 384    // KD/2  (half2 pairs along K)
#define NK4 192    // KD/4  (inner-loop chunks of 4 k-values)
#define BATCH 256
#define R 4        // batch rows per block
#define TPB 256    // threads per block: thread j owns cols {2j,2j+1} x rows 0..3
#define BPT 64     // blocks per tower (256 rows / R)

// fdot2: fp16 pair dot into fp32 accumulator (v_dot2_f32_f16)
static __device__ __forceinline__ float fdot2(f16x2 a, f16x2 b, float c) {
#if __has_builtin(__builtin_amdgcn_fdot2)
    return __builtin_amdgcn_fdot2(a, b, c, false);
#else
    return c + (float)a.x * (float)b.x + (float)a.y * (float)b.y;
#endif
}

static __device__ __forceinline__ f16x2 bc(float v) {
    return __builtin_bit_cast(f16x2, v);
}

// Pre-pass: pack W [768][512] fp32 into WB[k4][j][4] f16x2, where for chunk k0=4*k4:
//   slot0 = (W[k0+0][2j], W[k0+1][2j])    slot1 = (W[k0+0][2j+1], W[k0+1][2j+1])
//   slot2 = (W[k0+2][2j], W[k0+3][2j])    slot3 = (W[k0+2][2j+1], W[k0+3][2j+1])
// One float4 load per (k4) in the main loop then feeds 4 fdot2 ops per row.
__global__ void pack_w_kernel(const float* __restrict__ W, f16x2* __restrict__ WB) {
    const int idx = blockIdx.x * blockDim.x + threadIdx.x;   // (k4*256 + j)
    if (idx >= NK4 * 256) return;
    const int k4 = idx >> 8, j = idx & 255;
    const float* p = W + (size_t)(4 * k4) * HID;
    const int c0 = 2 * j, c1 = c0 + 1;
    f16x2 A, B, C, D;
    A.x = (f16)p[c0];            A.y = (f16)p[HID + c0];
    B.x = (f16)p[c1];            B.y = (f16)p[HID + c1];
    C.x = (f16)p[2 * HID + c0];  C.y = (f16)p[3 * HID + c0];
    D.x = (f16)p[2 * HID + c1];  D.y = (f16)p[3 * HID + c1];
    f16x2* o = WB + (size_t)idx * 4;
    o[0] = A; o[1] = B; o[2] = C; o[3] = D;
}

// Recurrent kernel. Block = R batch rows of one tower for the whole sequence.
// xh LDS layout: xh[buf][k2][r] as half2 = (v[r][2*k2], v[r][2*k2+1]) where v = [x_t | h].
// Per k4 chunk: 1 global float4 (W, coalesced 1KB/wave) + 2 broadcast ds_read_b128
// + 16 fdot2 (4 rows x 2 cols x 2 k-pairs). W read exactly once per block per step.
__global__ __launch_bounds__(TPB, 1)
void rnn_fp16_kernel(const float* __restrict__ qe, const float* __restrict__ pe,
                     const float* __restrict__ ne,
                     const f16x2* __restrict__ WBq, const f16x2* __restrict__ WBp,
                     const float* __restrict__ bq, const float* __restrict__ bp,
                     float* __restrict__ out) {
    const int tower = blockIdx.x / BPT;
    const int bblk  = blockIdx.x % BPT;

    const float* x; const float4* WB; const float* bias; float* o; int S;
    if (tower == 0)      { x = qe; WB = (const float4*)WBq; bias = bq; o = out;                 S = 64;  }
    else if (tower == 1) { x = pe; WB = (const float4*)WBp; bias = bp; o = out + BATCH * HID;   S = 256; }
    else                 { x = ne; WB = (const float4*)WBp; bias = bp; o = out + 2 * BATCH * HID; S = 256; }

    const int row0 = bblk * R;
    const int j = threadIdx.x;   // 0..255: column-pair owner

    __shared__ f16x2 xh[2][KD2][R];   // 12 KB, double-buffered

    // zero the h-region of buf0 (k2 in [128,384))
    {
        float* z = (float*)&xh[0][128][0];          // 256*R half2 = 1024 words
        for (int i = j; i < 256 * R; i += TPB) z[i] = 0.0f;
    }
    // stage x_0 into buf0 (k2 in [0,128))
    {
        const int r = j >> 6, e4 = (j & 63) * 4;
        const float4 v = *(const float4*)(x + ((size_t)(row0 + r) * S + 0) * EMBED + e4);
        f16x2 a; a.x = (f16)v.x; a.y = (f16)v.y;
        f16x2 b2; b2.x = (f16)v.z; b2.y = (f16)v.w;
        xh[0][(e4 >> 1)][r]     = a;
        xh[0][(e4 >> 1) + 1][r] = b2;
    }
    __syncthreads();

    const float b0 = bias[2 * j], b1 = bias[2 * j + 1];
    const float4* wp = WB + j;

    int buf = 0;
    for (int t = 0; t < S; ++t) {
        float a00 = b0, a01 = b1, a10 = b0, a11 = b1;
        float a20 = b0, a21 = b1, a30 = b0, a31 = b1;
#pragma unroll 8
        for (int k4 = 0; k4 < NK4; ++k4) {
            const float4 w = wp[(size_t)k4 * 256];
            const f16x2 wA = bc(w.x), wB = bc(w.y), wC = bc(w.z), wD = bc(w.w);
            const float4 x0 = *(const float4*)&xh[buf][2 * k4][0];       // rows 0..3, k-pair 2k4
            const float4 x1 = *(const float4*)&xh[buf][2 * k4 + 1][0];   // rows 0..3, k-pair 2k4+1
            a00 = fdot2(wA, bc(x0.x), a00);  a01 = fdot2(wB, bc(x0.x), a01);
            a10 = fdot2(wA, bc(x0.y), a10);  a11 = fdot2(wB, bc(x0.y), a11);
            a20 = fdot2(wA, bc(x0.z), a20);  a21 = fdot2(wB, bc(x0.z), a21);
            a30 = fdot2(wA, bc(x0.w), a30);  a31 = fdot2(wB, bc(x0.w), a31);
            a00 = fdot2(wC, bc(x1.x), a00);  a01 = fdot2(wD, bc(x1.x), a01);
            a10 = fdot2(wC, bc(x1.y), a10);  a11 = fdot2(wD, bc(x1.y), a11);
            a20 = fdot2(wC, bc(x1.z), a20);  a21 = fdot2(wD, bc(x1.z), a21);
            a30 = fdot2(wC, bc(x1.w), a30);  a31 = fdot2(wD, bc(x1.w), a31);
        }

        const float t00 = tanhf(a00), t01 = tanhf(a01);
        const float t10 = tanhf(a10), t11 = tanhf(a11);
        const float t20 = tanhf(a20), t21 = tanhf(a21);
        const float t30 = tanhf(a30), t31 = tanhf(a31);

        const int nb = buf ^ 1;
        if (t + 1 < S) {
            // publish h_{t+1}: thread owns cols {2j,2j+1} -> k2 = 128 + j
            f16x2 h0; h0.x = (f16)t00; h0.y = (f16)t01; xh[nb][128 + j][0] = h0;
            f16x2 h1; h1.x = (f16)t10; h1.y = (f16)t11; xh[nb][128 + j][1] = h1;
            f16x2 h2; h2.x = (f16)t20; h2.y = (f16)t21; xh[nb][128 + j][2] = h2;
            f16x2 h3; h3.x = (f16)t30; h3.y = (f16)t31; xh[nb][128 + j][3] = h3;
            // stage x_{t+1}
            const int r = j >> 6, e4 = (j & 63) * 4;
            const float4 v = *(const float4*)(x + ((size_t)(row0 + r) * S + (t + 1)) * EMBED + e4);
            f16x2 a; a.x = (f16)v.x; a.y = (f16)v.y;
            f16x2 b2; b2.x = (f16)v.z; b2.y = (f16)v.w;
            xh[nb][(e4 >> 1)][r]     = a;
            xh[nb][(e4 >> 1) + 1][r] = b2;
            __syncthreads();
        } else {
            *(float2*)(o + (size_t)(row0 + 0) * HID + 2 * j) = make_float2(t00, t01);
            *(float2*)(o + (size_t)(row0 + 1) * HID + 2 * j) = make_float2(t10, t11);
            *(float2*)(o + (size_t)(row0 + 2) * HID + 2 * j) = make_float2(t20, t21);
            *(float2*)(o + (size_t)(row0 + 3) * HID + 2 * j) = make_float2(t30, t31);
        }
        buf = nb;
    }
}

extern "C" void kernel_launch(void* const* d_in, const int* in_sizes, int n_in,
                              void* d_out, int out_size, void* d_ws, size_t ws_size,
                              hipStream_t stream) {
    const float* qe = (const float*)d_in[0];  // [256,64,256]
    const float* pe = (const float*)d_in[1];  // [256,256,256]
    const float* ne = (const float*)d_in[2];  // [256,256,256]
    const float* Wq = (const float*)d_in[3];  // [768,512]
    const float* bq = (const float*)d_in[4];  // [512]
    const float* Wp = (const float*)d_in[5];  // [768,512]
    const float* bp = (const float*)d_in[6];  // [512]
    float* out = (float*)d_out;               // q_vec | p_pos | p_neg

    (void)in_sizes; (void)n_in; (void)out_size; (void)ws_size;

    // ws: WBq (768KB) | WBp (768KB)
    f16x2* WBq = (f16x2*)d_ws;
    f16x2* WBp = WBq + (size_t)NK4 * 256 * 4;

    pack_w_kernel<<<NK4, TPB, 0, stream>>>(Wq, WBq);
    pack_w_kernel<<<NK4, TPB, 0, stream>>>(Wp, WBp);

    rnn_fp16_kernel<<<3 * BPT, TPB, 0, stream>>>(qe, pe, ne, WBq, WBp, bq, bp, out);
}

// Round 3
// 3400.610 us; speedup vs baseline: 1.2037x; 1.2037x over previous
//
#include <hip/hip_runtime.h>

typedef _Float16 f16;
typedef _Float16 f16x2 __attribute__((ext_vector_type(2)));
typedef _Float16 f16x8 __attribute__((ext_vector_type(8)));
typedef float f32x4 __attribute__((ext_vector_type(4)));
typedef unsigned int u32;

#define EMB 256
#define HID 512
#define KD 768
#define NT 32      // n-tiles (512/16)
#define KS 24      // k-steps total (768/32): ks 0..15 = h (Wh), ks 16..23 = x (Wx)
#define MROWS 32
#define TPB 512
#define XP_OFF (2u << 20)
#define XP_REC 32768               // bytes per (grp,t) record: 32x512 fp16
#define N_REC 4608                 // 8*64 (q) + 8*256 (pos) + 8*256 (neg)

#define MFMA16(A,B,C) __builtin_amdgcn_mfma_f32_16x16x32_f16(A,B,C,0,0,0)
#define BC8(u)  __builtin_bit_cast(f16x8, u)
#define BCU(p)  __builtin_bit_cast(u32, p)

__device__ __forceinline__ float fast_tanh(float a) {
    a = fminf(10.0f, fmaxf(-10.0f, a));
    float e = __expf(2.0f * a);
    return 1.0f - __fdividef(2.0f, e + 1.0f);
}

// ---------------------------------------------------------------------------
// Pack W [768][512] fp32 -> fragment-linear fp16 WB[(nt*KS+ks)*64 + lane] (16B each).
// Lane's 8 f16 = W[korig(k0..k0+7)][col], col = nt*16+(lane&15), k0 = ks*32+(lane>>4)*8.
// k in [0,512) -> korig = k+256 (Wh);  k in [512,768) -> korig = k-512 (Wx).
__global__ void pack_w(const float* __restrict__ W, uint4* __restrict__ WB) {
    const int idx = blockIdx.x * 256 + threadIdx.x;
    if (idx >= NT * KS * 64) return;
    const int l = idx & 63, rest = idx >> 6, ks = rest % KS, nt = rest / KS;
    const int col = nt * 16 + (l & 15);
    const int k0 = ks * 32 + (l >> 4) * 8;
    u32 d[4];
#pragma unroll
    for (int i = 0; i < 4; ++i) {
        const int ka = k0 + 2 * i, kb = ka + 1;
        const int koa = (ka < 512) ? ka + 256 : ka - 512;
        const int kob = (kb < 512) ? kb + 256 : kb - 512;
        f16x2 p;
        p.x = (f16)W[(size_t)koa * HID + col];
        p.y = (f16)W[(size_t)kob * HID + col];
        d[i] = BCU(p);
    }
    WB[idx] = make_uint4(d[0], d[1], d[2], d[3]);
}

// ---------------------------------------------------------------------------
// xproj: xp(grp,t)[32 rows][512 cols] = x_t @ Wx + bias, stored fp16 in
// C-fragment-linear order: offset = ((w*8 + m2*4 + n4)*64 + lane)*8 bytes,
// lane's uint2 = fp16(acc[0..3] + bias).
__global__ __launch_bounds__(TPB, 1)
void xproj_kernel(const float* __restrict__ qe, const float* __restrict__ pe,
                  const float* __restrict__ ne,
                  const uint4* __restrict__ WBq, const uint4* __restrict__ WBp,
                  const float* __restrict__ bq, const float* __restrict__ bp,
                  char* __restrict__ xp) {
    const int bid = blockIdx.x;
    int grp, t, S; const float* x; const uint4* WBt; const float* bias;
    if (bid < 512)       { grp = bid >> 6; t = bid & 63;  S = 64;  x = qe; WBt = WBq; bias = bq; }
    else if (bid < 2560) { int b = bid - 512;  grp = b >> 8; t = b & 255; S = 256; x = pe; WBt = WBp; bias = bp; }
    else                 { int b = bid - 2560; grp = b >> 8; t = b & 255; S = 256; x = ne; WBt = WBp; bias = bp; }

    __shared__ __align__(16) f16 xs[MROWS * EMB];   // 16 KB, XOR-swizzled
    char* xb = (char*)xs;
    const int tid = threadIdx.x, l = tid & 63, w = tid >> 6;
    const int lr = l & 15, lq = l >> 4;

    // stage x tile [32][256] fp32 -> fp16 LDS
    {
        const int r = tid >> 4, kk = (tid & 15) * 16;
        const float* xg = x + ((size_t)(grp * 32 + r) * S + t) * EMB + kk;
        const float4 v0 = *(const float4*)(xg + 0),  v1 = *(const float4*)(xg + 4);
        const float4 v2 = *(const float4*)(xg + 8),  v3 = *(const float4*)(xg + 12);
        u32 q[8]; f16x2 pp;
        pp.x = (f16)v0.x; pp.y = (f16)v0.y; q[0] = BCU(pp);
        pp.x = (f16)v0.z; pp.y = (f16)v0.w; q[1] = BCU(pp);
        pp.x = (f16)v1.x; pp.y = (f16)v1.y; q[2] = BCU(pp);
        pp.x = (f16)v1.z; pp.y = (f16)v1.w; q[3] = BCU(pp);
        pp.x = (f16)v2.x; pp.y = (f16)v2.y; q[4] = BCU(pp);
        pp.x = (f16)v2.z; pp.y = (f16)v2.w; q[5] = BCU(pp);
        pp.x = (f16)v3.x; pp.y = (f16)v3.y; q[6] = BCU(pp);
        pp.x = (f16)v3.z; pp.y = (f16)v3.w; q[7] = BCU(pp);
        const u32 rsw = ((u32)(r & 7)) << 4;
        const u32 b0 = ((u32)(r * 512 + kk * 2)) ^ rsw;
        const u32 b1 = ((u32)(r * 512 + kk * 2 + 16)) ^ rsw;
        *(uint4*)(xb + b0) = make_uint4(q[0], q[1], q[2], q[3]);
        *(uint4*)(xb + b1) = make_uint4(q[4], q[5], q[6], q[7]);
    }
    __syncthreads();

    const u32 sw  = ((u32)(lr & 7)) << 4;
    const u32 ab0 = (u32)(lr * 512 + lq * 16);
    const u32 ab1 = (u32)((lr + 16) * 512 + lq * 16);
    const uint4* wbx = WBt + ((size_t)(w * 4 * KS + 16)) * 64 + l;

    f32x4 acc00 = {0,0,0,0}, acc01 = {0,0,0,0}, acc02 = {0,0,0,0}, acc03 = {0,0,0,0};
    f32x4 acc10 = {0,0,0,0}, acc11 = {0,0,0,0}, acc12 = {0,0,0,0}, acc13 = {0,0,0,0};
#pragma unroll
    for (int ksl = 0; ksl < 8; ++ksl) {
        const uint4 af0 = *(const uint4*)(xb + ((ab0 + (u32)ksl * 64) ^ sw));
        const uint4 af1 = *(const uint4*)(xb + ((ab1 + (u32)ksl * 64) ^ sw));
        const uint4 bf0 = wbx[(size_t)(0 * KS + ksl) * 64];
        const uint4 bf1 = wbx[(size_t)(1 * KS + ksl) * 64];
        const uint4 bf2 = wbx[(size_t)(2 * KS + ksl) * 64];
        const uint4 bf3 = wbx[(size_t)(3 * KS + ksl) * 64];
        const f16x8 A0 = BC8(af0), A1 = BC8(af1);
        acc00 = MFMA16(A0, BC8(bf0), acc00); acc10 = MFMA16(A1, BC8(bf0), acc10);
        acc01 = MFMA16(A0, BC8(bf1), acc01); acc11 = MFMA16(A1, BC8(bf1), acc11);
        acc02 = MFMA16(A0, BC8(bf2), acc02); acc12 = MFMA16(A1, BC8(bf2), acc12);
        acc03 = MFMA16(A0, BC8(bf3), acc03); acc13 = MFMA16(A1, BC8(bf3), acc13);
    }

    char* xpo = xp + (size_t)bid * XP_REC + (size_t)l * 8;
    const float b0v = bias[(w * 4 + 0) * 16 + lr];
    const float b1v = bias[(w * 4 + 1) * 16 + lr];
    const float b2v = bias[(w * 4 + 2) * 16 + lr];
    const float b3v = bias[(w * 4 + 3) * 16 + lr];
#define XPW(m2, n4, ACC, BV) { \
    f16x2 lo, hi; \
    lo.x = (f16)(ACC[0] + BV); lo.y = (f16)(ACC[1] + BV); \
    hi.x = (f16)(ACC[2] + BV); hi.y = (f16)(ACC[3] + BV); \
    uint2 o; o.x = BCU(lo); o.y = BCU(hi); \
    *(uint2*)(xpo + (size_t)((w * 8 + (m2) * 4 + (n4)) * 64) * 8) = o; }
    XPW(0, 0, acc00, b0v); XPW(0, 1, acc01, b1v); XPW(0, 2, acc02, b2v); XPW(0, 3, acc03, b3v);
    XPW(1, 0, acc10, b0v); XPW(1, 1, acc11, b1v); XPW(1, 2, acc12, b2v); XPW(1, 3, acc13, b3v);
#undef XPW
}

// ---------------------------------------------------------------------------
// Recurrent kernel: block = 32 batch rows of one tower, 8 waves (wave w owns
// cols w*64..+64). A = [h | x_t] fp16 in XOR-swizzled LDS [32][768]; W as
// fragment-linear global (direct-to-VGPR B loads, no LDS). 2 barriers/step.
template<int XP>
__global__ __launch_bounds__(TPB, 1)
void rnn_mfma(const float* __restrict__ qe, const float* __restrict__ pe,
              const float* __restrict__ ne,
              const uint4* __restrict__ WBq, const uint4* __restrict__ WBp,
              const float* __restrict__ bq, const float* __restrict__ bp,
              const char* __restrict__ xp, float* __restrict__ out) {
    const int bid = blockIdx.x;
    int grp, S, rec0; const float* x; const uint4* WBt; const float* bias; float* o;
    if (bid < 8)       { grp = bid;      S = 256; x = pe; WBt = WBp; bias = bp; o = out + 131072; rec0 = 512 + grp * 256; }
    else if (bid < 16) { grp = bid - 8;  S = 256; x = ne; WBt = WBp; bias = bp; o = out + 262144; rec0 = 2560 + grp * 256; }
    else               { grp = bid - 16; S = 64;  x = qe; WBt = WBq; bias = bq; o = out;          rec0 = grp * 64; }
    o += (size_t)grp * 32 * HID;

    __shared__ __align__(16) f16 As[MROWS * KD];   // 48 KB
    char* Asb = (char*)As;
    const int tid = threadIdx.x, l = tid & 63, w = tid >> 6;
    const int lr = l & 15, lq = l >> 4;
    const u32 sw  = ((u32)(lr & 7)) << 4;
    const u32 ab0 = (u32)(lr * 1536 + lq * 16);
    const u32 ab1 = (u32)((lr + 16) * 1536 + lq * 16);

    // zero h region (bytes 0..1024 of each row)
    {
        const int r = tid >> 4; const u32 k0b = (u32)((tid & 15) * 64);
        const u32 rb = (u32)(r * 1536), rsw = ((u32)(r & 7)) << 4;
        const uint4 z = make_uint4(0, 0, 0, 0);
        *(uint4*)(Asb + ((rb + k0b +  0) ^ rsw)) = z;
        *(uint4*)(Asb + ((rb + k0b + 16) ^ rsw)) = z;
        *(uint4*)(Asb + ((rb + k0b + 32) ^ rsw)) = z;
        *(uint4*)(Asb + ((rb + k0b + 48) ^ rsw)) = z;
    }
    const int sr = tid >> 4, skk = (tid & 15) * 16;       // staging coords (!XP)
    const u32 srsw = ((u32)(sr & 7)) << 4;
    const u32 sb0 = ((u32)(sr * 1536 + 1024 + skk * 2)) ^ srsw;
    const u32 sb1 = ((u32)(sr * 1536 + 1024 + skk * 2 + 16)) ^ srsw;
#define CVT16(v0, v1, v2, v3, Q) { f16x2 pp; \
    pp.x=(f16)v0.x; pp.y=(f16)v0.y; Q[0]=BCU(pp); pp.x=(f16)v0.z; pp.y=(f16)v0.w; Q[1]=BCU(pp); \
    pp.x=(f16)v1.x; pp.y=(f16)v1.y; Q[2]=BCU(pp); pp.x=(f16)v1.z; pp.y=(f16)v1.w; Q[3]=BCU(pp); \
    pp.x=(f16)v2.x; pp.y=(f16)v2.y; Q[4]=BCU(pp); pp.x=(f16)v2.z; pp.y=(f16)v2.w; Q[5]=BCU(pp); \
    pp.x=(f16)v3.x; pp.y=(f16)v3.y; Q[6]=BCU(pp); pp.x=(f16)v3.z; pp.y=(f16)v3.w; Q[7]=BCU(pp); }
    if (!XP) {  // stage x_0
        const float* xg = x + ((size_t)(grp * 32 + sr) * S) * EMB + skk;
        const float4 v0 = *(const float4*)(xg + 0),  v1 = *(const float4*)(xg + 4);
        const float4 v2 = *(const float4*)(xg + 8),  v3 = *(const float4*)(xg + 12);
        u32 q[8]; CVT16(v0, v1, v2, v3, q);
        *(uint4*)(Asb + sb0) = make_uint4(q[0], q[1], q[2], q[3]);
        *(uint4*)(Asb + sb1) = make_uint4(q[4], q[5], q[6], q[7]);
    }
    __syncthreads();

    float bs0 = 0.f, bs1 = 0.f, bs2 = 0.f, bs3 = 0.f;
    if (!XP) {
        bs0 = bias[(w * 4 + 0) * 16 + lr]; bs1 = bias[(w * 4 + 1) * 16 + lr];
        bs2 = bias[(w * 4 + 2) * 16 + lr]; bs3 = bias[(w * 4 + 3) * 16 + lr];
    }
    const uint4* wb = WBt + (size_t)(w * 4 * KS) * 64 + l;
    const char* xpr = xp + (size_t)rec0 * XP_REC + ((size_t)(w * 8) * 64 + l) * 8;

    for (int t = 0; t < S; ++t) {
        uint2 xf00, xf01, xf02, xf03, xf10, xf11, xf12, xf13;
        if (XP) {
            const char* xr = xpr + (size_t)t * XP_REC;
            xf00 = *(const uint2*)(xr + 0 * 512); xf01 = *(const uint2*)(xr + 1 * 512);
            xf02 = *(const uint2*)(xr + 2 * 512); xf03 = *(const uint2*)(xr + 3 * 512);
            xf10 = *(const uint2*)(xr + 4 * 512); xf11 = *(const uint2*)(xr + 5 * 512);
            xf12 = *(const uint2*)(xr + 6 * 512); xf13 = *(const uint2*)(xr + 7 * 512);
        }
        float4 xn0, xn1, xn2, xn3;
        if (!XP && t + 1 < S) {   // prefetch x_{t+1} (hidden under k-loop)
            const float* xg = x + ((size_t)(grp * 32 + sr) * S + (t + 1)) * EMB + skk;
            xn0 = *(const float4*)(xg + 0);  xn1 = *(const float4*)(xg + 4);
            xn2 = *(const float4*)(xg + 8);  xn3 = *(const float4*)(xg + 12);
        }
        f32x4 acc00 = {0,0,0,0}, acc01 = {0,0,0,0}, acc02 = {0,0,0,0}, acc03 = {0,0,0,0};
        f32x4 acc10 = {0,0,0,0}, acc11 = {0,0,0,0}, acc12 = {0,0,0,0}, acc13 = {0,0,0,0};
#define KSTEP(ks) { \
    const uint4 af0 = *(const uint4*)(Asb + ((ab0 + (u32)(ks) * 64) ^ sw)); \
    const uint4 af1 = *(const uint4*)(Asb + ((ab1 + (u32)(ks) * 64) ^ sw)); \
    const uint4 bf0 = wb[(size_t)(0 * KS + (ks)) * 64]; \
    const uint4 bf1 = wb[(size_t)(1 * KS + (ks)) * 64]; \
    const uint4 bf2 = wb[(size_t)(2 * KS + (ks)) * 64]; \
    const uint4 bf3 = wb[(size_t)(3 * KS + (ks)) * 64]; \
    const f16x8 A0 = BC8(af0), A1 = BC8(af1); \
    acc00 = MFMA16(A0, BC8(bf0), acc00); acc10 = MFMA16(A1, BC8(bf0), acc10); \
    acc01 = MFMA16(A0, BC8(bf1), acc01); acc11 = MFMA16(A1, BC8(bf1), acc11); \
    acc02 = MFMA16(A0, BC8(bf2), acc02); acc12 = MFMA16(A1, BC8(bf2), acc12); \
    acc03 = MFMA16(A0, BC8(bf3), acc03); acc13 = MFMA16(A1, BC8(bf3), acc13); }
        if (XP) {
            if (t > 0) {
#pragma unroll
                for (int ks = 0; ks < 16; ++ks) KSTEP(ks);
            }
        } else if (t == 0) {
#pragma unroll
            for (int ks = 16; ks < 24; ++ks) KSTEP(ks);
        } else {
#pragma unroll
            for (int ks = 0; ks < 24; ++ks) KSTEP(ks);
        }
#undef KSTEP
        __syncthreads();   // all waves done reading A before h rewrite

        const bool last = (t == S - 1);
#define EPI(m2, n4, ACC, XF, BV) { \
    float a0, a1, a2, a3; \
    if (XP) { const f16x2 lo = __builtin_bit_cast(f16x2, XF.x); \
              const f16x2 hi = __builtin_bit_cast(f16x2, XF.y); \
              a0 = (float)lo.x; a1 = (float)lo.y; a2 = (float)hi.x; a3 = (float)hi.y; } \
    else { a0 = a1 = a2 = a3 = BV; } \
    const int col = (w * 4 + (n4)) * 16 + lr; \
    const float h0 = fast_tanh(ACC[0] + a0), h1 = fast_tanh(ACC[1] + a1); \
    const float h2 = fast_tanh(ACC[2] + a2), h3 = fast_tanh(ACC[3] + a3); \
    const int r0 = (m2) * 16 + lq * 4; \
    if (last) { \
        o[(size_t)(r0 + 0) * HID + col] = h0; o[(size_t)(r0 + 1) * HID + col] = h1; \
        o[(size_t)(r0 + 2) * HID + col] = h2; o[(size_t)(r0 + 3) * HID + col] = h3; \
    } else { \
        const u32 cb = (u32)(col * 2); \
        *(f16*)(Asb + (((u32)((r0 + 0) * 1536) + cb) ^ (((u32)((r0 + 0) & 7)) << 4))) = (f16)h0; \
        *(f16*)(Asb + (((u32)((r0 + 1) * 1536) + cb) ^ (((u32)((r0 + 1) & 7)) << 4))) = (f16)h1; \
        *(f16*)(Asb + (((u32)((r0 + 2) * 1536) + cb) ^ (((u32)((r0 + 2) & 7)) << 4))) = (f16)h2; \
        *(f16*)(Asb + (((u32)((r0 + 3) * 1536) + cb) ^ (((u32)((r0 + 3) & 7)) << 4))) = (f16)h3; \
    } }
        EPI(0, 0, acc00, xf00, bs0); EPI(0, 1, acc01, xf01, bs1);
        EPI(0, 2, acc02, xf02, bs2); EPI(0, 3, acc03, xf03, bs3);
        EPI(1, 0, acc10, xf10, bs0); EPI(1, 1, acc11, xf11, bs1);
        EPI(1, 2, acc12, xf12, bs2); EPI(1, 3, acc13, xf13, bs3);
#undef EPI
        if (!XP && !last) {  // write staged x_{t+1}
            u32 q[8]; CVT16(xn0, xn1, xn2, xn3, q);
            *(uint4*)(Asb + sb0) = make_uint4(q[0], q[1], q[2], q[3]);
            *(uint4*)(Asb + sb1) = make_uint4(q[4], q[5], q[6], q[7]);
        }
        if (!last) __syncthreads();
    }
#undef CVT16
}

extern "C" void kernel_launch(void* const* d_in, const int* in_sizes, int n_in,
                              void* d_out, int out_size, void* d_ws, size_t ws_size,
                              hipStream_t stream) {
    const float* qe = (const float*)d_in[0];
    const float* pe = (const float*)d_in[1];
    const float* ne = (const float*)d_in[2];
    const float* Wq = (const float*)d_in[3];
    const float* bq = (const float*)d_in[4];
    const float* Wp = (const float*)d_in[5];
    const float* bp = (const float*)d_in[6];
    float* out = (float*)d_out;
    (void)in_sizes; (void)n_in; (void)out_size;

    char* ws = (char*)d_ws;
    uint4* WBq = (uint4*)ws;                       // 768 KB
    uint4* WBp = (uint4*)(ws + 786432);            // 768 KB
    char*  xp  = ws + XP_OFF;                      // 144 MB (fragment-packed xproj)
    const size_t need = (size_t)XP_OFF + (size_t)N_REC * XP_REC;
    const bool use_xp = (ws_size >= need);

    pack_w<<<NT * KS * 64 / 256, 256, 0, stream>>>(Wq, WBq);
    pack_w<<<NT * KS * 64 / 256, 256, 0, stream>>>(Wp, WBp);
    if (use_xp) {
        xproj_kernel<<<N_REC, TPB, 0, stream>>>(qe, pe, ne, WBq, WBp, bq, bp, xp);
        rnn_mfma<1><<<24, TPB, 0, stream>>>(qe, pe, ne, WBq, WBp, bq, bp, xp, out);
    } else {
        rnn_mfma<0><<<24, TPB, 0, stream>>>(qe, pe, ne, WBq, WBp, bq, bp, xp, out);
    }
}

// Round 5
// 1730.091 us; speedup vs baseline: 2.3660x; 1.9656x over previous
//
#include <hip/hip_runtime.h>

typedef _Float16 f16;
typedef _Float16 f16x2 __attribute__((ext_vector_type(2)));
typedef _Float16 f16x8 __attribute__((ext_vector_type(8)));
typedef float f32x4 __attribute__((ext_vector_type(4)));
typedef unsigned int u32;

#define EMB 256
#define HID 512
#define NT 32        // n-tiles (512/16)
#define KS 24        // WB k-steps: 0..15 = h (Wh rows 256..767), 16..23 = x (Wx rows 0..255)
#define M 16         // batch rows per block
#define TPB 512      // 8 waves; wave w owns cols [64w, 64w+64)
#define T8 8         // timesteps per xproj block
#define XP_OFF (2u << 20)
#define XP_REC 16384 // bytes per (grp,t) record: 16x512 fp16, C-fragment-linear
#define N_REC 9216   // q 16*64 + pos 16*256 + neg 16*256

// rnn LDS map: Hb[2][16 rows][1024B] @0 (32KB) | Xs[16][512B] @32768 (8KB) | W3L 8w*4KB @40960 (32KB)
#define LDS_XS 32768
#define LDS_W3 40960
#define LDS_TOT 73728

#define MFMA16(A,B,C) __builtin_amdgcn_mfma_f32_16x16x32_f16(A,B,C,0,0,0)
#define BC8(u)  __builtin_bit_cast(f16x8, u)
#define BCU(p)  __builtin_bit_cast(u32, p)

__device__ __forceinline__ float fast_tanh(float a) {
    a = fminf(10.0f, fmaxf(-10.0f, a));
    float e = __expf(2.0f * a);
    return 1.0f - __fdividef(2.0f, e + 1.0f);
}

// ---------------------------------------------------------------------------
// pack_w: UNCHANGED (HW-verified round 3).
// WB[(nt*KS + ks)*64 + lane]: lane's 8 f16 = W[korig(k0..k0+7)][col],
// col = nt*16+(l&15), k0 = ks*32+(l>>4)*8; k<512 -> korig=k+256 (Wh), else k-512 (Wx).
__global__ void pack_w(const float* __restrict__ W, uint4* __restrict__ WB) {
    const int idx = blockIdx.x * 256 + threadIdx.x;
    if (idx >= NT * KS * 64) return;
    const int l = idx & 63, rest = idx >> 6, ks = rest % KS, nt = rest / KS;
    const int col = nt * 16 + (l & 15);
    const int k0 = ks * 32 + (l >> 4) * 8;
    u32 d[4];
#pragma unroll
    for (int i = 0; i < 4; ++i) {
        const int ka = k0 + 2 * i, kb = ka + 1;
        const int koa = (ka < 512) ? ka + 256 : ka - 512;
        const int kob = (kb < 512) ? kb + 256 : kb - 512;
        f16x2 p;
        p.x = (f16)W[(size_t)koa * HID + col];
        p.y = (f16)W[(size_t)kob * HID + col];
        d[i] = BCU(p);
    }
    WB[idx] = make_uint4(d[0], d[1], d[2], d[3]);
}

// ---------------------------------------------------------------------------
// xproj (T8=8 timesteps/block): xp(rec) = x_t @ Wx + bias, fp16 C-fragment-linear
// (frag w*4+n4 at byte ((w*4+n4)*64+lane)*8). Wx frags read once per 8 records.
__global__ __launch_bounds__(TPB, 2)
void xproj_kernel(const float* __restrict__ qe, const float* __restrict__ pe,
                  const float* __restrict__ ne,
                  const uint4* __restrict__ WBq, const uint4* __restrict__ WBp,
                  const float* __restrict__ bq, const float* __restrict__ bp,
                  char* __restrict__ xp) {
    const int b = blockIdx.x;
    int grp, t0, S, rec0; const float* x; const uint4* WBt; const float* bias;
    if (b < 128)      { grp = b >> 3;           t0 = (b & 7) * T8;   S = 64;  x = qe; WBt = WBq; bias = bq; rec0 = grp * 64 + t0; }
    else if (b < 640) { const int c = b - 128;  grp = c >> 5; t0 = (c & 31) * T8; S = 256; x = pe; WBt = WBp; bias = bp; rec0 = 1024 + grp * 256 + t0; }
    else              { const int c = b - 640;  grp = c >> 5; t0 = (c & 31) * T8; S = 256; x = ne; WBt = WBp; bias = bp; rec0 = 5120 + grp * 256 + t0; }

    __shared__ __align__(16) f16 xs[T8 * M * EMB];  // 64 KB
    char* xb = (char*)xs;
    const int tid = threadIdx.x, l = tid & 63, w = tid >> 6;
    const int lr = l & 15, lq = l >> 4;

    {   // stage 8 x-slices [16][256] fp32 -> fp16 (swizzled rows)
        const int r = tid >> 5, kk = (tid & 31) * 8;
        const u32 db = ((u32)(r * 512 + kk * 2)) ^ (((u32)(r & 7)) << 4);
#pragma unroll
        for (int tt = 0; tt < T8; ++tt) {
            const float* xg = x + ((size_t)(grp * M + r) * S + (t0 + tt)) * EMB + kk;
            const float4 v0 = *(const float4*)(xg + 0), v1 = *(const float4*)(xg + 4);
            u32 q[4]; f16x2 pp;
            pp.x = (f16)v0.x; pp.y = (f16)v0.y; q[0] = BCU(pp);
            pp.x = (f16)v0.z; pp.y = (f16)v0.w; q[1] = BCU(pp);
            pp.x = (f16)v1.x; pp.y = (f16)v1.y; q[2] = BCU(pp);
            pp.x = (f16)v1.z; pp.y = (f16)v1.w; q[3] = BCU(pp);
            *(uint4*)(xb + (u32)(tt * 8192) + db) = make_uint4(q[0], q[1], q[2], q[3]);
        }
    }
    __syncthreads();

    const u32 sw = ((u32)(lr & 7)) << 4;
    const u32 ab = (u32)(lr * 512 + lq * 16);
    const uint4* wbx = WBt + ((size_t)(w * 4) * KS + 16) * 64 + l;

    f32x4 acc[T8][4];
#pragma unroll
    for (int tt = 0; tt < T8; ++tt)
#pragma unroll
        for (int n = 0; n < 4; ++n) acc[tt][n] = (f32x4){0.f, 0.f, 0.f, 0.f};

#pragma unroll
    for (int ksl = 0; ksl < 8; ++ksl) {
        const uint4 b0 = wbx[(size_t)(0 * KS + ksl) * 64];
        const uint4 b1 = wbx[(size_t)(1 * KS + ksl) * 64];
        const uint4 b2 = wbx[(size_t)(2 * KS + ksl) * 64];
        const uint4 b3 = wbx[(size_t)(3 * KS + ksl) * 64];
#pragma unroll
        for (int tt = 0; tt < T8; ++tt) {
            const uint4 af = *(const uint4*)(xb + (u32)(tt * 8192) + ((ab + (u32)(ksl * 64)) ^ sw));
            const f16x8 A = BC8(af);
            acc[tt][0] = MFMA16(A, BC8(b0), acc[tt][0]);
            acc[tt][1] = MFMA16(A, BC8(b1), acc[tt][1]);
            acc[tt][2] = MFMA16(A, BC8(b2), acc[tt][2]);
            acc[tt][3] = MFMA16(A, BC8(b3), acc[tt][3]);
        }
    }

    const float bv0 = bias[(w * 4 + 0) * 16 + lr];
    const float bv1 = bias[(w * 4 + 1) * 16 + lr];
    const float bv2 = bias[(w * 4 + 2) * 16 + lr];
    const float bv3 = bias[(w * 4 + 3) * 16 + lr];
#pragma unroll
    for (int tt = 0; tt < T8; ++tt) {
        char* xpo = xp + (size_t)(rec0 + tt) * XP_REC + ((size_t)(w * 4) * 64 + (size_t)l) * 8;
#define XPW(n4, BV) { \
        const f32x4 A = acc[tt][n4]; \
        f16x2 lo, hi; \
        lo.x = (f16)(A[0] + BV); lo.y = (f16)(A[1] + BV); \
        hi.x = (f16)(A[2] + BV); hi.y = (f16)(A[3] + BV); \
        uint2 o2; o2.x = BCU(lo); o2.y = BCU(hi); \
        *(uint2*)(xpo + (n4) * 512) = o2; }
        XPW(0, bv0); XPW(1, bv1); XPW(2, bv2); XPW(3, bv3);
#undef XPW
    }
}

// ---------------------------------------------------------------------------
// Recurrent kernel. M=16 rows/block, 8 waves. W residency: n4 0..2 (48 frags,
// 192 VGPR) pinned; n4=3: ks 12..15 in wave-private LDS (preloaded once),
// ks 0..11 streamed via 4-deep rotating queue (loop-invariant addrs).
// h double-buffered in LDS -> 1 barrier/step (XP path).
template<int XP>
__global__ __launch_bounds__(TPB, 2)
void rnn_mfma(const float* __restrict__ qe, const float* __restrict__ pe,
              const float* __restrict__ ne,
              const uint4* __restrict__ WBq, const uint4* __restrict__ WBp,
              const float* __restrict__ bq, const float* __restrict__ bp,
              const char* __restrict__ xp, float* __restrict__ out) {
    const int bid = blockIdx.x;
    int grp, S, rec0; const float* x; const uint4* WBt; const float* bias; float* o;
    if (bid < 16)      { grp = bid;      S = 256; x = pe; WBt = WBp; bias = bp; o = out + 131072; rec0 = 1024 + grp * 256; }
    else if (bid < 32) { grp = bid - 16; S = 256; x = ne; WBt = WBp; bias = bp; o = out + 262144; rec0 = 5120 + grp * 256; }
    else               { grp = bid - 32; S = 64;  x = qe; WBt = WBq; bias = bq; o = out;          rec0 = grp * 64; }
    o += (size_t)grp * M * HID;

    __shared__ __align__(16) char smem[LDS_TOT];
    const int tid = threadIdx.x, l = tid & 63, w = tid >> 6;
    const int lr = l & 15, lq = l >> 4;
    const u32 sw = ((u32)(lr & 7)) << 4;
    const u32 hbase = (u32)(lr * 1024 + lq * 16);
    const u32 w3a = (u32)(LDS_W3 + w * 4096 + l * 16);

    // ---- W residency (n4 0..2, 48 frags)
    const uint4* wb = WBt + (size_t)(w * 4) * KS * 64 + l;
    uint4 Wr[3][16];
#pragma unroll
    for (int n4 = 0; n4 < 3; ++n4)
#pragma unroll
        for (int ks = 0; ks < 16; ++ks)
            Wr[n4][ks] = wb[(size_t)(n4 * KS + ks) * 64];
    // n4=3: stream queue (frags 0..11) + wave-private LDS (frags 12..15)
    const uint4* wb3 = wb + (size_t)(3 * KS) * 64;
    uint4 S3[4];
#pragma unroll
    for (int i = 0; i < 4; ++i) S3[i] = wb3[(size_t)i * 64];
#pragma unroll
    for (int f = 0; f < 4; ++f) {
        const uint4 v = wb3[(size_t)(12 + f) * 64];
        *(uint4*)(smem + w3a + (u32)(f * 1024)) = v;   // wave-private: no barrier needed
    }

    const int sr = tid >> 5, skk = (tid & 31) * 8;
    const u32 sb = (u32)LDS_XS + (((u32)(sr * 512 + skk * 2)) ^ (((u32)(sr & 7)) << 4));
#define CVTST(v0, v1, DST) { u32 q[4]; f16x2 pp; \
    pp.x=(f16)v0.x; pp.y=(f16)v0.y; q[0]=BCU(pp); pp.x=(f16)v0.z; pp.y=(f16)v0.w; q[1]=BCU(pp); \
    pp.x=(f16)v1.x; pp.y=(f16)v1.y; q[2]=BCU(pp); pp.x=(f16)v1.z; pp.y=(f16)v1.w; q[3]=BCU(pp); \
    *(uint4*)(DST) = make_uint4(q[0], q[1], q[2], q[3]); }
    if (!XP) {  // stage x_0
        const float* xg = x + ((size_t)(grp * M + sr) * S) * EMB + skk;
        const float4 v0 = *(const float4*)(xg + 0), v1 = *(const float4*)(xg + 4);
        CVTST(v0, v1, smem + sb);
    }
    __syncthreads();

    float bs0 = 0.f, bs1 = 0.f, bs2 = 0.f, bs3 = 0.f;
    if (!XP) {
        bs0 = bias[(w * 4 + 0) * 16 + lr]; bs1 = bias[(w * 4 + 1) * 16 + lr];
        bs2 = bias[(w * 4 + 2) * 16 + lr]; bs3 = bias[(w * 4 + 3) * 16 + lr];
    }
    const char* xpr = xp + (size_t)rec0 * XP_REC + (size_t)(w * 2048 + l * 8);

    for (int t = 0; t < S; ++t) {
        uint2 xf0, xf1, xf2, xf3;
        if (XP) {   // prefetched at step start, consumed in EPI
            const char* xr = xpr + (size_t)t * XP_REC;
            xf0 = *(const uint2*)(xr +    0); xf1 = *(const uint2*)(xr +  512);
            xf2 = *(const uint2*)(xr + 1024); xf3 = *(const uint2*)(xr + 1536);
        }
        float4 xn0, xn1;
        if (!XP && t + 1 < S) {
            const float* xg = x + ((size_t)(grp * M + sr) * S + (t + 1)) * EMB + skk;
            xn0 = *(const float4*)(xg + 0); xn1 = *(const float4*)(xg + 4);
        }
        f32x4 a0, a1, a2, a3;
        if (XP) { a0 = (f32x4){0,0,0,0}; a1 = a0; a2 = a0; a3 = a0; }
        else    { a0 = (f32x4){bs0,bs0,bs0,bs0}; a1 = (f32x4){bs1,bs1,bs1,bs1};
                  a2 = (f32x4){bs2,bs2,bs2,bs2}; a3 = (f32x4){bs3,bs3,bs3,bs3}; }

        const u32 rb = (u32)((t & 1) << 14);   // h read buffer
        if (t > 0) {
#pragma unroll
            for (int ks = 0; ks < 16; ++ks) {
                const uint4 af = *(const uint4*)(smem + rb + ((hbase + (u32)(ks * 64)) ^ sw));
                const f16x8 A = BC8(af);
                a0 = MFMA16(A, BC8(Wr[0][ks]), a0);
                a1 = MFMA16(A, BC8(Wr[1][ks]), a1);
                a2 = MFMA16(A, BC8(Wr[2][ks]), a2);
                if (ks < 12) {
                    a3 = MFMA16(A, BC8(S3[ks & 3]), a3);
                    S3[ks & 3] = wb3[(size_t)((ks + 4) % 12) * 64];  // refill, 4-ks lead
                } else {
                    const uint4 w3 = *(const uint4*)(smem + w3a + (u32)((ks - 12) * 1024));
                    a3 = MFMA16(A, BC8(w3), a3);
                }
            }
        }
        if (!XP) {  // x-part ks 16..23: A from Xs, all 4 B-frags streamed
#pragma unroll
            for (int ks = 16; ks < 24; ++ks) {
                const u32 xo = (u32)LDS_XS + (((u32)(lr * 512 + lq * 16 + (ks - 16) * 64)) ^ sw);
                const uint4 af = *(const uint4*)(smem + xo);
                const uint4 b0 = wb[(size_t)(0 * KS + ks) * 64];
                const uint4 b1 = wb[(size_t)(1 * KS + ks) * 64];
                const uint4 b2 = wb[(size_t)(2 * KS + ks) * 64];
                const uint4 b3 = wb[(size_t)(3 * KS + ks) * 64];
                const f16x8 A = BC8(af);
                a0 = MFMA16(A, BC8(b0), a0); a1 = MFMA16(A, BC8(b1), a1);
                a2 = MFMA16(A, BC8(b2), a2); a3 = MFMA16(A, BC8(b3), a3);
            }
            __syncthreads();   // Xs readers done before rewrite
        }

        const bool last = (t == S - 1);
        const u32 wbuf = (u32)(((t + 1) & 1) << 14);   // h write buffer
#define EPI(n4, ACC, XF) { \
    float e0, e1, e2, e3; \
    if (XP) { const f16x2 lo2 = __builtin_bit_cast(f16x2, XF.x); \
              const f16x2 hi2 = __builtin_bit_cast(f16x2, XF.y); \
              e0 = (float)lo2.x; e1 = (float)lo2.y; e2 = (float)hi2.x; e3 = (float)hi2.y; } \
    else { e0 = e1 = e2 = e3 = 0.f; } \
    const int col = (w * 4 + (n4)) * 16 + lr; \
    const float h0 = fast_tanh(ACC[0] + e0), h1 = fast_tanh(ACC[1] + e1); \
    const float h2 = fast_tanh(ACC[2] + e2), h3 = fast_tanh(ACC[3] + e3); \
    const int r0 = lq * 4; \
    if (last) { \
        o[(size_t)(r0 + 0) * HID + col] = h0; o[(size_t)(r0 + 1) * HID + col] = h1; \
        o[(size_t)(r0 + 2) * HID + col] = h2; o[(size_t)(r0 + 3) * HID + col] = h3; \
    } else { \
        const u32 cb = (u32)(col * 2); \
        *(f16*)(smem + wbuf + (u32)((r0 + 0) * 1024) + (cb ^ (((u32)((r0 + 0) & 7)) << 4))) = (f16)h0; \
        *(f16*)(smem + wbuf + (u32)((r0 + 1) * 1024) + (cb ^ (((u32)((r0 + 1) & 7)) << 4))) = (f16)h1; \
        *(f16*)(smem + wbuf + (u32)((r0 + 2) * 1024) + (cb ^ (((u32)((r0 + 2) & 7)) << 4))) = (f16)h2; \
        *(f16*)(smem + wbuf + (u32)((r0 + 3) * 1024) + (cb ^ (((u32)((r0 + 3) & 7)) << 4))) = (f16)h3; \
    } }
        EPI(0, a0, xf0); EPI(1, a1, xf1); EPI(2, a2, xf2); EPI(3, a3, xf3);
#undef EPI
        if (!XP && !last) {   // publish x_{t+1}
            CVTST(xn0, xn1, smem + sb);
        }
        if (!last) __syncthreads();
    }
#undef CVTST
}

extern "C" void kernel_launch(void* const* d_in, const int* in_sizes, int n_in,
                              void* d_out, int out_size, void* d_ws, size_t ws_size,
                              hipStream_t stream) {
    const float* qe = (const float*)d_in[0];
    const float* pe = (const float*)d_in[1];
    const float* ne = (const float*)d_in[2];
    const float* Wq = (const float*)d_in[3];
    const float* bq = (const float*)d_in[4];
    const float* Wp = (const float*)d_in[5];
    const float* bp = (const float*)d_in[6];
    float* out = (float*)d_out;
    (void)in_sizes; (void)n_in; (void)out_size;

    char* ws = (char*)d_ws;
    uint4* WBq = (uint4*)ws;                       // 768 KB
    uint4* WBp = (uint4*)(ws + 786432);            // 768 KB
    char*  xp  = ws + XP_OFF;                      // 144 MiB
    const size_t need = (size_t)XP_OFF + (size_t)N_REC * XP_REC;
    const bool use_xp = (ws_size >= need);

    pack_w<<<NT * KS * 64 / 256, 256, 0, stream>>>(Wq, WBq);
    pack_w<<<NT * KS * 64 / 256, 256, 0, stream>>>(Wp, WBp);
    if (use_xp) {
        xproj_kernel<<<1152, TPB, 0, stream>>>(qe, pe, ne, WBq, WBp, bq, bp, xp);
        rnn_mfma<1><<<48, TPB, 0, stream>>>(qe, pe, ne, WBq, WBp, bq, bp, xp, out);
    } else {
        rnn_mfma<0><<<48, TPB, 0, stream>>>(qe, pe, ne, WBq, WBp, bq, bp, xp, out);
    }
}